// Round 7
// baseline (524.831 us; speedup 1.0000x reference)
//
#include <hip/hip_runtime.h>
#include <hip/hip_bf16.h>
#include <hip/hip_fp16.h>
#include <cstdint>

// FlipLinear: out[M,N] = x[M,K] @ W[N,K]^T, W = ternary * scales[group].
// M=8192, N=4096, K=4096.
//
// R7: 256x256 8-phase fp16 GEMM, SINGLE barrier per phase.
// R6 post-mortem: 2-barrier phases serialized LDS-read segment (730 cyc/CU)
// and MFMA segment (621 cyc/CU) -> 1252 cyc phases, 47% MfmaUtil. The
// pre-MFMA barrier is provably redundant:
//  - WAR (stage overwrites just-read region): stage at phase p targets the
//    region last ds_read at p-1. Every wave's lgkmcnt (compiler-inserted
//    before its MFMAs) completes its reads before it reaches barrier(p-1);
//    stages are issued after passing that barrier. MFMA drain reads only
//    registers -> safe.
//  - RAW (read flipped buffer): p4/p8 per-wave vmcnt(6) fence + the same
//    collective barrier => all waves' stages for the flipped buffer landed
//    before any wave's next-phase ds_reads.
// Single barrier lets waves skew within a phase: one wave's MFMAs overlap
// another's ds_reads -> phase ~ max(LDS, MFMA) instead of sum.
// Fence moved after the MFMA cluster (drains under compute).
// Plus bijective XCD swizzle (nwg=512 = 8*64): wgid = (orig&7)*64 + orig>>3.
//
// vmcnt accounting (2 units per stage_half, audited R5/R6):
//  prologue 7 halves (14) -> FENCE6 drains tile0 (buf0) before p1.
//  steady p4 FENCE6 -> drains through t(2it+1).Ak1 => buf1 complete for p5-p8.
//  steady p8 FENCE6 -> drains through t(2it+2).Ak1 => buf0 complete for p1-p4.
//  tail iter: p4 uses FENCE0 (steady-state count breaks; covers p1's stage).

using f16x8  = __attribute__((ext_vector_type(8))) _Float16;
using f32x4  = __attribute__((ext_vector_type(4))) float;
using i32x4  = __attribute__((ext_vector_type(4))) int;

constexpr int M_DIM = 8192;
constexpr int N_DIM = 4096;
constexpr int K_DIM = 4096;
constexpr int BM = 256, BN = 256, BK = 64;
constexpr int GRID_N = N_DIM / BN;   // 16
constexpr int GRID_M = M_DIM / BM;   // 32
constexpr int NIT    = K_DIM / (2 * BK);  // 32 iterations, 2 K-tiles each

constexpr size_t XH_ELEMS = (size_t)M_DIM * K_DIM;
constexpr size_t WH_ELEMS = (size_t)N_DIM * K_DIM;

// ---------------------------------------------------------------- precompute
__global__ __launch_bounds__(256)
void xcvt(const float* __restrict__ x, _Float16* __restrict__ xh) {
  const size_t idx = (size_t)blockIdx.x * 256 + threadIdx.x;
  const f32x4* src = reinterpret_cast<const f32x4*>(x) + idx * 2;
  f32x4 a = src[0], b = src[1];
  f16x8 h;
#pragma unroll
  for (int j = 0; j < 8; ++j) h[j] = (_Float16)((j < 4) ? a[j] : b[j - 4]);
  reinterpret_cast<f16x8*>(xh)[idx] = h;
}

__global__ __launch_bounds__(256)
void wcvt(const int* __restrict__ tern, const float* __restrict__ scales,
          _Float16* __restrict__ wh) {
  const size_t idx = (size_t)blockIdx.x * 256 + threadIdx.x;
  const float s = scales[idx >> 4];
  const i32x4* src = reinterpret_cast<const i32x4*>(tern) + idx * 2;
  i32x4 a = src[0], b = src[1];
  f16x8 h;
#pragma unroll
  for (int j = 0; j < 8; ++j) {
    int v = (j < 4) ? a[j] : b[j - 4];
    h[j] = (_Float16)(s * (float)v);
  }
  reinterpret_cast<f16x8*>(wh)[idx] = h;
}

// ---------------------------------------------------------------- main GEMM
#define FENCE6 asm volatile("s_waitcnt vmcnt(6)" ::: "memory")
#define FENCE0 asm volatile("s_waitcnt vmcnt(0)" ::: "memory")

__global__ __launch_bounds__(512, 2)
void flip_gemm_8ph(const _Float16* __restrict__ xh, const _Float16* __restrict__ wh,
                   float* __restrict__ out) {
  // 128 KiB LDS: [buf][ks][row][swizzled col], 16KB per (buf,ks) plane.
  __shared__ __align__(16) _Float16 sA[2][2][256][32];
  __shared__ __align__(16) _Float16 sB[2][2][256][32];

  const int t    = threadIdx.x;            // 0..511
  const int orig = blockIdx.x;             // 512 blocks = 8 XCDs * 64
  const int bid  = (orig & 7) * 64 + (orig >> 3);   // bijective XCD swizzle
  const int bn   = bid & (GRID_N - 1);
  const int bm   = bid >> 4;
  const int rowBase = bm * BM;
  const int colBase = bn * BN;

  const int wid  = t >> 6;                 // 0..7
  const int lane = t & 63;
  const int wm   = wid >> 2;               // 2 M-waves
  const int wn   = wid & 3;                // 4 N-waves
  const int lr   = lane & 15;
  const int lk   = lane >> 4;              // 0..3

  f32x4 acc[8][4];
#pragma unroll
  for (int m = 0; m < 8; ++m)
#pragma unroll
    for (int n = 0; n < 4; ++n) acc[m][n] = f32x4{0.f, 0.f, 0.f, 0.f};

  // stage one K-half (256 rows x 32 kcols = 16KB) of tile kt into ldsBase.
  // Linear LDS dest (wave-uniform base + lane*16); swizzle in global source.
  auto stage_half = [&](const _Float16* __restrict__ src, _Float16* ldsBase,
                        int gRowBase, int kt, int ks) {
#pragma unroll
    for (int i = 0; i < 2; ++i) {
      const int q0  = i * 512 + wid * 64;        // wave-uniform chunk base
      const int q   = q0 + lane;                 // chunk in [0,1024)
      const int row = q >> 2;
      const int c4  = (q & 3) ^ ((row >> 1) & 3);
      const _Float16* g = src + (size_t)(gRowBase + row) * K_DIM + kt * 64 + ks * 32 + c4 * 8;
      __builtin_amdgcn_global_load_lds(
          (const __attribute__((address_space(1))) unsigned int*)g,
          (__attribute__((address_space(3))) unsigned int*)(ldsBase + q0 * 8), 16, 0, 0);
    }
  };

// Phase: {ds_read frags | stage | MFMA (setprio) | fence? | ONE barrier}.
#define PHASE(MH, KS, RB, READB, STAGE_STMT, FENCE_STMT)                              \
  do {                                                                                \
    f16x8 Af[4];                                                                      \
    if (READB) {                                                                      \
      _Pragma("unroll") for (int fn = 0; fn < 4; ++fn) {                              \
        const int row = wn * 64 + fn * 16 + lr;                                       \
        Bfrag[fn] = *reinterpret_cast<const f16x8*>(                                  \
            &sB[RB][KS][row][(lk ^ ((row >> 1) & 3)) * 8]);                           \
      }                                                                               \
    }                                                                                 \
    _Pragma("unroll") for (int fm = 0; fm < 4; ++fm) {                                \
      const int row = wm * 128 + MH * 64 + fm * 16 + lr;                              \
      Af[fm] = *reinterpret_cast<const f16x8*>(                                       \
          &sA[RB][KS][row][(lk ^ ((row >> 1) & 3)) * 8]);                             \
    }                                                                                 \
    STAGE_STMT;                                                                       \
    __builtin_amdgcn_s_setprio(1);                                                    \
    _Pragma("unroll") for (int fm = 0; fm < 4; ++fm)                                  \
      _Pragma("unroll") for (int fn = 0; fn < 4; ++fn)                                \
        acc[MH * 4 + fm][fn] = __builtin_amdgcn_mfma_f32_16x16x32_f16(                \
            Af[fm], Bfrag[fn], acc[MH * 4 + fm][fn], 0, 0, 0);                        \
    __builtin_amdgcn_s_setprio(0);                                                    \
    FENCE_STMT;                                                                       \
    __builtin_amdgcn_s_barrier();                                                     \
  } while (0)

  // Prologue: tile0 fully + tile1 first 3 halves; vmcnt(6) => tile0 landed.
  stage_half(wh, &sB[0][0][0][0], colBase, 0, 0);
  stage_half(xh, &sA[0][0][0][0], rowBase, 0, 0);
  stage_half(wh, &sB[0][1][0][0], colBase, 0, 1);
  stage_half(xh, &sA[0][1][0][0], rowBase, 0, 1);
  stage_half(wh, &sB[1][0][0][0], colBase, 1, 0);
  stage_half(xh, &sA[1][0][0][0], rowBase, 1, 0);
  stage_half(wh, &sB[1][1][0][0], colBase, 1, 1);
  FENCE6;
  __builtin_amdgcn_s_barrier();

  f16x8 Bfrag[4];
  for (int it = 0; it < NIT; ++it) {
    const int t2 = 2 * it + 2;           // next even tile -> buf0
    const int t3 = 2 * it + 3;           // next odd tile  -> buf1
    const bool st = (it < NIT - 1);

    // p1: compute buf0 (mh0,ks0); stage current odd tile's Ak1 -> buf1
    PHASE(0, 0, 0, true,  { stage_half(xh, &sA[1][1][0][0], rowBase, 2 * it + 1, 1); }, {});
    // p2: compute buf0 (mh1,ks0, B reuse); stage t2.Bk0 -> buf0
    PHASE(1, 0, 0, false, { if (st) stage_half(wh, &sB[0][0][0][0], colBase, t2, 0); }, {});
    // p3: compute buf0 (mh0,ks1); stage t2.Ak0 -> buf0
    PHASE(0, 1, 0, true,  { if (st) stage_half(xh, &sA[0][0][0][0], rowBase, t2, 0); }, {});
    // p4: compute buf0 (mh1,ks1); stage t2.Bk1 -> buf0; FENCE => buf1 ready
    PHASE(1, 1, 0, false, { if (st) stage_half(wh, &sB[0][1][0][0], colBase, t2, 1); },
          { if (st) { FENCE6; } else { FENCE0; } });
    // p5: compute buf1 (mh0,ks0); stage t2.Ak1 -> buf0
    PHASE(0, 0, 1, true,  { if (st) stage_half(xh, &sA[0][1][0][0], rowBase, t2, 1); }, {});
    // p6: compute buf1 (mh1,ks0, B reuse); stage t3.Bk0 -> buf1
    PHASE(1, 0, 1, false, { if (st) stage_half(wh, &sB[1][0][0][0], colBase, t3, 0); }, {});
    // p7: compute buf1 (mh0,ks1); stage t3.Ak0 -> buf1
    PHASE(0, 1, 1, true,  { if (st) stage_half(xh, &sA[1][0][0][0], rowBase, t3, 0); }, {});
    // p8: compute buf1 (mh1,ks1); stage t3.Bk1 -> buf1; FENCE => buf0 ready
    PHASE(1, 1, 1, false, { if (st) stage_half(wh, &sB[1][1][0][0], colBase, t3, 1); },
          { if (st) { FENCE6; } });
  }

  // Epilogue: C layout col = lane&15, row = (lane>>4)*4 + j (R1/R4-verified).
#pragma unroll
  for (int mf = 0; mf < 8; ++mf)
#pragma unroll
    for (int fn = 0; fn < 4; ++fn) {
      const int col = colBase + wn * 64 + fn * 16 + lr;
#pragma unroll
      for (int j = 0; j < 4; ++j) {
        const int row = rowBase + wm * 128 + mf * 16 + lk * 4 + j;
        out[(size_t)row * N_DIM + col] = acc[mf][fn][j];
      }
    }
}

extern "C" void kernel_launch(void* const* d_in, const int* in_sizes, int n_in,
                              void* d_out, int out_size, void* d_ws, size_t ws_size,
                              hipStream_t stream) {
  const float* x      = (const float*)d_in[0];
  const int*   tern   = (const int*)d_in[1];
  const float* scales = (const float*)d_in[2];
  float* out          = (float*)d_out;

  _Float16* xh = (_Float16*)d_ws;
  _Float16* wh = xh + XH_ELEMS;
  xcvt<<<dim3(XH_ELEMS / (256 * 8)), dim3(256), 0, stream>>>(x, xh);
  wcvt<<<dim3(WH_ELEMS / (256 * 8)), dim3(256), 0, stream>>>(tern, scales, wh);
  flip_gemm_8ph<<<dim3(GRID_M * GRID_N), dim3(512), 0, stream>>>(xh, wh, out);
  (void)ws_size; (void)in_sizes; (void)n_in; (void)out_size;
}